// Round 22
// baseline (245.334 us; speedup 1.0000x reference)
//
#include <hip/hip_runtime.h>
#include <hip/hip_bf16.h>

// Fused LayerNorm + QKV projection for B=4, S=2048, H=2048 (fp32 in/out).
//
// Round 22: r21 (merged prologue, 224.8us) with the GEMM's MFMA shape
// switched 16x16x32 -> 32x32x16 (measured 2075 vs 2382-2495 TF ceilings:
// per-phase MFMA 621 -> 516 cyc at identical FLOP and identical LDS traffic).
// Fragment geometry: wave tile 128x64 = 4 m-frags x 2 n-frags of 32x32,
// acc[4][2] f32x16 = 128 AGPR (same budget). All 8 B-frags (bf[2][4],
// 32 VGPR) load at each K-tile's first phase so B's LDS reads stay in the
// r15 slots -> stage slots + VM6/VM0 ledger carry over verbatim (passed 7x).
// Same [256][64] XOR-swizzled LDS + coalesced staging (2-way bank aliasing
// within 16-lane groups = free, same as r15's measured 0 conflicts).

#define HD   2048            // hidden dim (K)
#define MTOT 8192            // B*S rows
#define NTOT 6144            // 3*H packed output cols
#define NIT  16              // iterations (2 K-tiles of BK=64 each)

typedef __attribute__((ext_vector_type(8)))  _Float16 f16x8;   // 4 VGPR
typedef __attribute__((ext_vector_type(4)))  _Float16 f16x4;
typedef __attribute__((ext_vector_type(16))) float f32x16;     // 16 AGPR

// ---------------------------------------------------------------------------
// Kernel 1 (merged prologue): blocks [0, MTOT) do LayerNorm->fp16; blocks
// [MTOT, MTOT+3072) convert the three weight matrices to fp16.
// ---------------------------------------------------------------------------
__global__ __launch_bounds__(256) void prep_kernel(
    const float* __restrict__ x, const float* __restrict__ gamma,
    const float* __restrict__ beta, const float* __restrict__ qw,
    const float* __restrict__ kw, const float* __restrict__ vw,
    _Float16* __restrict__ Ah, _Float16* __restrict__ Wh) {
  const int t = threadIdx.x;

  if (blockIdx.x < MTOT) {
    const int row = blockIdx.x;
    const float* xr = x + (size_t)row * HD;

    float4 v0 = reinterpret_cast<const float4*>(xr)[t * 2];
    float4 v1 = reinterpret_cast<const float4*>(xr)[t * 2 + 1];
    float xs[8] = {v0.x, v0.y, v0.z, v0.w, v1.x, v1.y, v1.z, v1.w};

    float s = 0.f, q = 0.f;
#pragma unroll
    for (int j = 0; j < 8; ++j) { s += xs[j]; q += xs[j] * xs[j]; }
#pragma unroll
    for (int off = 32; off; off >>= 1) {
      s += __shfl_down(s, off);
      q += __shfl_down(q, off);
    }
    __shared__ float red[8];
    const int wid = t >> 6, lane = t & 63;
    if (lane == 0) { red[wid] = s; red[4 + wid] = q; }
    __syncthreads();
    s = red[0] + red[1] + red[2] + red[3];
    q = red[4] + red[5] + red[6] + red[7];
    const float mu  = s * (1.f / HD);
    const float var = q * (1.f / HD) - mu * mu;
    const float rs  = rsqrtf(var + 1e-5f);

    float4 g0 = reinterpret_cast<const float4*>(gamma)[t * 2];
    float4 g1 = reinterpret_cast<const float4*>(gamma)[t * 2 + 1];
    float4 b0 = reinterpret_cast<const float4*>(beta)[t * 2];
    float4 b1 = reinterpret_cast<const float4*>(beta)[t * 2 + 1];
    float gs[8] = {g0.x, g0.y, g0.z, g0.w, g1.x, g1.y, g1.z, g1.w};
    float bs[8] = {b0.x, b0.y, b0.z, b0.w, b1.x, b1.y, b1.z, b1.w};

    f16x8 hv;
#pragma unroll
    for (int j = 0; j < 8; ++j) {
      float y = (xs[j] - mu) * rs * gs[j] + bs[j];
      hv[j] = (_Float16)y;
    }
    *reinterpret_cast<f16x8*>(&Ah[(size_t)row * HD + t * 8]) = hv;
  } else {
    const int wb = blockIdx.x - MTOT;        // 0..3071
    const int m  = wb / 1024;
    const int b0 = wb % 1024;
    const float* src = (m == 0) ? qw : (m == 1) ? kw : vw;
    const size_t base = (size_t)m * HD * HD;
    const int total4 = HD * HD / 4;
    for (int i = b0 * 256 + t; i < total4; i += 1024 * 256) {
      float4 v = reinterpret_cast<const float4*>(src)[i];
      f16x4 hv;
      hv[0] = (_Float16)v.x; hv[1] = (_Float16)v.y;
      hv[2] = (_Float16)v.z; hv[3] = (_Float16)v.w;
      *reinterpret_cast<f16x4*>(&Wh[base + (size_t)i * 4]) = hv;
    }
  }
}

// ---------------------------------------------------------------------------
// Kernel 2: 256x256 8-phase GEMM on v_mfma_f32_32x32x16_f16.
// out[m][n] = sum_k A[m][k] * W_p[n][k] + bias_p[n]
//
// LDS (128 KiB, f16): A bufs @ {0,16384}, B bufs @ {32768,49152}; each buf =
// row-major [256][64] f16; slot s of row r holds k-chunk s^(r&7); staging
// loads global column ((t&7)^((t>>3)&7)) -> line-coalesced (r15, 0 confl).
//
// Wave tile 128x64: 4 m-frags x 2 n-frags of 32x32; K-tile 64 = 4 chunks of
// K=16.  Input layout: lane l holds row/col l&31, k = (l>>5)*8 + j.
//   kc[ks2] = ((ks2*2 + (l>>5)) ^ (l&7)) * 8  (per-thread constants).
// Phases per K-tile (buf): P+0: BLD all 8 B-frags + A(mh0,ksh0), MFMA 8;
//   P+1: A(mh1,ksh0), MFMA 8; P+2: A(mh0,ksh1), MFMA 8; P+3: A(mh1,ksh1),
//   MFMA 8.  mh0 reads A rows h0 (0-63/128-191), mh1 h1; B LDS-reads only
//   at P+0 -> region read-slots match r15 exactly.
// Stage slots + guards (= r15..r21, passed): P0:stA(1,1,kt1) P1:stB(0,0,kt2)
//   P2:stB(0,1,kt2) P3:stA(0,0,kt2)+VM6(VM0 last) P4:stA(0,1,kt2)
//   P5:stB(1,0,kt3) P6:stB(1,1,kt3) P7:stA(1,0,kt3)+VM6.
// C/D layout (m74/m101-verified): col = lane&31,
//   row = (reg&3) + 8*(reg>>2) + 4*(lane>>5).
// ---------------------------------------------------------------------------
__device__ __forceinline__ void gload16(const _Float16* g, _Float16* l) {
  __builtin_amdgcn_global_load_lds(
      (const __attribute__((address_space(1))) void*)g,
      (__attribute__((address_space(3))) void*)l, 16, 0, 0);
}

#define BAR()   asm volatile("s_barrier" ::: "memory")
#define LGKM0() asm volatile("s_waitcnt lgkmcnt(0)" ::: "memory")
#define VM6()   asm volatile("s_waitcnt vmcnt(6)" ::: "memory")
#define VM0()   asm volatile("s_waitcnt vmcnt(0)" ::: "memory")

#define LA(BUF, MI, KC) \
  (*(const f16x8*)(lds + (BUF)*16384 + rA + (MI)*2048 + (KC)))
#define LB(BUF, NI, KC) \
  (*(const f16x8*)(lds + 32768 + (BUF)*16384 + rB + (NI)*2048 + (KC)))

#define BLD8(BUF) do { \
    bf[0][0]=LB(BUF,0,kc0); bf[0][1]=LB(BUF,0,kc1); \
    bf[0][2]=LB(BUF,0,kc2); bf[0][3]=LB(BUF,0,kc3); \
    bf[1][0]=LB(BUF,1,kc0); bf[1][1]=LB(BUF,1,kc1); \
    bf[1][2]=LB(BUF,1,kc2); bf[1][3]=LB(BUF,1,kc3); \
  } while (0)
// Load the 4 A-frags for (MH, ksh): mi = MH*2+{0,1}, k-chunks KCA/KCB.
#define ALD4(BUF, MH, KCA, KCB) do { \
    a00 = LA(BUF, (MH)*2+0, KCA); a01 = LA(BUF, (MH)*2+0, KCB); \
    a10 = LA(BUF, (MH)*2+1, KCA); a11 = LA(BUF, (MH)*2+1, KCB); \
  } while (0)

#define MF32(A, B, C) __builtin_amdgcn_mfma_f32_32x32x16_f16(A, B, C, 0, 0, 0)
#define MFMAS2(MH, KSH) do { \
    __builtin_amdgcn_s_setprio(1); \
    acc[(MH)*2+0][0] = MF32(a00, bf[0][(KSH)*2+0], acc[(MH)*2+0][0]); \
    acc[(MH)*2+0][0] = MF32(a01, bf[0][(KSH)*2+1], acc[(MH)*2+0][0]); \
    acc[(MH)*2+0][1] = MF32(a00, bf[1][(KSH)*2+0], acc[(MH)*2+0][1]); \
    acc[(MH)*2+0][1] = MF32(a01, bf[1][(KSH)*2+1], acc[(MH)*2+0][1]); \
    acc[(MH)*2+1][0] = MF32(a10, bf[0][(KSH)*2+0], acc[(MH)*2+1][0]); \
    acc[(MH)*2+1][0] = MF32(a11, bf[0][(KSH)*2+1], acc[(MH)*2+1][0]); \
    acc[(MH)*2+1][1] = MF32(a10, bf[1][(KSH)*2+0], acc[(MH)*2+1][1]); \
    acc[(MH)*2+1][1] = MF32(a11, bf[1][(KSH)*2+1], acc[(MH)*2+1][1]); \
    __builtin_amdgcn_s_setprio(0); \
  } while (0)

__global__ __launch_bounds__(512, 2) void qkv_gemm_kernel(
    const _Float16* __restrict__ Ah, const _Float16* __restrict__ Wh,
    const float* __restrict__ qb, const float* __restrict__ kb,
    const float* __restrict__ vb, float* __restrict__ out) {
  extern __shared__ _Float16 lds[];   // 131072 B

  const int t      = threadIdx.x;
  const int lane   = t & 63;
  const int wid    = t >> 6;          // 0..7
  const int wm     = wid >> 2;        // 0..1 (M)
  const int wn     = wid & 3;         // 0..3 (N)
  const int lane32 = lane & 31;
  const int hi     = lane >> 5;       // 0..1 (k-chunk half)

  const int n0  = blockIdx.x * 256;
  const int m0  = blockIdx.y * 256;
  const int p   = n0 >> 11;
  const int ln0 = n0 & (HD - 1);
  const _Float16* Ag  = Ah + (size_t)m0 * HD;
  const _Float16* Bgp = Wh + (size_t)p * HD * HD + (size_t)ln0 * HD;
  const float* bias = (p == 0) ? qb : (p == 1) ? kb : vb;

  // Staging invariants (coalesced + inverse-swizzled source).
  const int srow = t >> 3;                              // 0..63
  const int scol = ((t & 7) ^ (srow & 7)) * 8;          // f16 offset in row
  // Fragment-read invariants (f16 offsets).
  const int rA  = (wm * 128 + lane32) * 64;
  const int rB  = (wn * 64 + lane32) * 64;
  const int kc0 = ((0 * 2 + hi) ^ (lane & 7)) * 8;
  const int kc1 = ((1 * 2 + hi) ^ (lane & 7)) * 8;
  const int kc2 = ((2 * 2 + hi) ^ (lane & 7)) * 8;
  const int kc3 = ((3 * 2 + hi) ^ (lane & 7)) * 8;

  auto stA = [&](int buf, int hf, int kt) {
    const _Float16* g = Ag + (size_t)(hf * 64 + srow) * HD + kt * 64 + scol;
    _Float16* l = lds + buf * 16384 + (hf * 512 + t) * 8;
    gload16(g, l);
    gload16(g + (size_t)128 * HD, l + 8192);
  };
  auto stB = [&](int buf, int hf, int kt) {
    const _Float16* g = Bgp + (size_t)(hf * 64 + srow) * HD + kt * 64 + scol;
    _Float16* l = lds + 32768 + buf * 16384 + (hf * 512 + t) * 8;
    gload16(g, l);
    gload16(g + (size_t)128 * HD, l + 8192);
  };

  f32x16 acc[4][2] = {};

  // Fragment registers: B set bf[2][4] (32 VGPR) + A ephemeral (16 VGPR).
  f16x8 bf[2][4];
  f16x8 a00, a01, a10, a11;

  // Prologue: buf0 <- K-tile 0 (4 halves), buf1 <- K-tile 1 (3 halves).
  // vmcnt(6) = 3 calls in flight -> buf0 fully landed.
  stB(0, 0, 0); stB(0, 1, 0); stA(0, 0, 0); stA(0, 1, 0);
  stB(1, 0, 1); stB(1, 1, 1); stA(1, 0, 1);
  VM6();
  BAR();

#pragma unroll 1
  for (int i = 0; i < NIT; ++i) {
    const bool nl = (i < NIT - 1);
    const int kt1 = 2 * i + 1, kt2 = 2 * i + 2, kt3 = 2 * i + 3;

    // ---- P0: buf0 (mh0, ksh0); BLD all B0 ----
    stA(1, 1, kt1);
    BLD8(0);
    ALD4(0, 0, kc0, kc1);
    MFMAS2(0, 0);
    LGKM0(); BAR();

    // ---- P1: buf0 (mh1, ksh0) ----
    if (nl) stB(0, 0, kt2);
    ALD4(0, 1, kc0, kc1);
    MFMAS2(1, 0);
    LGKM0(); BAR();

    // ---- P2: buf0 (mh0, ksh1) ----
    if (nl) stB(0, 1, kt2);
    ALD4(0, 0, kc2, kc3);
    MFMAS2(0, 1);
    LGKM0(); BAR();

    // ---- P3: buf0 (mh1, ksh1); guard buf1 ----
    if (nl) stA(0, 0, kt2);
    ALD4(0, 1, kc2, kc3);
    MFMAS2(1, 1);
    LGKM0();
    if (nl) { VM6(); } else { VM0(); }        // buf1 content landed
    BAR();

    // ---- P4: buf1 (mh0, ksh0); BLD all B1 ----
    if (nl) stA(0, 1, kt2);
    BLD8(1);
    ALD4(1, 0, kc0, kc1);
    MFMAS2(0, 0);
    LGKM0(); BAR();

    // ---- P5: buf1 (mh1, ksh0) ----
    if (nl) stB(1, 0, kt3);
    ALD4(1, 1, kc0, kc1);
    MFMAS2(1, 0);
    LGKM0(); BAR();

    // ---- P6: buf1 (mh0, ksh1) ----
    if (nl) stB(1, 1, kt3);
    ALD4(1, 0, kc2, kc3);
    MFMAS2(0, 1);
    LGKM0(); BAR();

    // ---- P7: buf1 (mh1, ksh1); guard buf0@kt2 ----
    if (nl) stA(1, 0, kt3);
    ALD4(1, 1, kc2, kc3);
    MFMAS2(1, 1);
    LGKM0();
    if (nl) { VM6(); }                        // buf0 content landed
    BAR();
  }

  // Epilogue: 32x32 C/D layout col = lane&31, row = (reg&3)+8*(reg>>2)+4*hi.
  float bv[2];
#pragma unroll
  for (int ni = 0; ni < 2; ++ni)
    bv[ni] = bias[ln0 + wn * 64 + ni * 32 + lane32];
#pragma unroll
  for (int mi = 0; mi < 4; ++mi) {
#pragma unroll
    for (int ni = 0; ni < 2; ++ni) {
      const int cg = n0 + wn * 64 + ni * 32 + lane32;
      f32x16 v = acc[mi][ni];
#pragma unroll
      for (int reg = 0; reg < 16; ++reg) {
        const int row = (reg & 3) + 8 * (reg >> 2) + 4 * hi;
        out[(size_t)(m0 + wm * 128 + mi * 32 + row) * NTOT + cg] =
            v[reg] + bv[ni];
      }
    }
  }
}

// ---------------------------------------------------------------------------
extern "C" void kernel_launch(void* const* d_in, const int* in_sizes, int n_in,
                              void* d_out, int out_size, void* d_ws,
                              size_t ws_size, hipStream_t stream) {
  const float* x     = (const float*)d_in[0];
  const float* gamma = (const float*)d_in[1];
  const float* beta  = (const float*)d_in[2];
  const float* qw    = (const float*)d_in[3];
  const float* qb    = (const float*)d_in[4];
  const float* kw    = (const float*)d_in[5];
  const float* kbia  = (const float*)d_in[6];
  const float* vw    = (const float*)d_in[7];
  const float* vb    = (const float*)d_in[8];
  float* out = (float*)d_out;

  // Workspace: [0, 32M) normed fp16 [8192][2048]; [32M, 56M) W fp16 [3][2048][2048]
  char* ws = (char*)d_ws;
  _Float16* Ahp = (_Float16*)(ws);
  _Float16* Whp = (_Float16*)(ws + (size_t)MTOT * HD * 2);

  (void)hipFuncSetAttribute((const void*)qkv_gemm_kernel,
                            hipFuncAttributeMaxDynamicSharedMemorySize, 131072);

  prep_kernel<<<MTOT + 3072, 256, 0, stream>>>(x, gamma, beta, qw, kw, vw,
                                               Ahp, Whp);
  qkv_gemm_kernel<<<dim3(NTOT / 256, MTOT / 256), 512, 131072, stream>>>(
      Ahp, Whp, qb, kbia, vb, out);
}

// Round 23
// 224.210 us; speedup vs baseline: 1.0942x; 1.0942x over previous
//
#include <hip/hip_runtime.h>
#include <hip/hip_bf16.h>

// Fused LayerNorm + QKV projection for B=4, S=2048, H=2048 (fp32 in/out).
//
// Round 23 = REVERT to round 21 (best measured: 224.8us total, GEMM 196us).
// r22's 32x32x16 MFMA port was numerically correct but introduced 1.9e7 LDS
// bank conflicts (+24us) - reverted. Final configuration:
//  - merged prologue (LN->fp16 + W->fp16, one launch, ~28us, HBM-bound)
//  - 256x256/BK=64/8-wave GEMM on mfma_f32_16x16x32_f16
//  - row-major [256][64] XOR-swizzled LDS, line-coalesced global_load_lds
//    (inverse-swizzled source), 0 bank conflicts
//  - full A+B one-phase register lookahead, counted phase-end lgkm fences,
//    counted vmcnt(6) ledger (never 0 in steady state), setprio on MFMA
// K-loop is LDS-bandwidth-bound (phase 1224 cyc vs 960-cyc LDS floor +
// 621-cyc MFMA floor); r15-r20 proved scheduling variants are all neutral.

#define HD   2048            // hidden dim (K)
#define MTOT 8192            // B*S rows
#define NTOT 6144            // 3*H packed output cols
#define NIT  16              // iterations (2 K-tiles of BK=64 each)

typedef __attribute__((ext_vector_type(8))) _Float16 f16x8;   // 4 VGPR
typedef __attribute__((ext_vector_type(4))) _Float16 f16x4;
typedef __attribute__((ext_vector_type(4))) float f32x4;

// ---------------------------------------------------------------------------
// Kernel 1 (merged prologue): blocks [0, MTOT) do LayerNorm->fp16 (one row
// each); blocks [MTOT, MTOT+3072) convert the three weight matrices to fp16.
// ---------------------------------------------------------------------------
__global__ __launch_bounds__(256) void prep_kernel(
    const float* __restrict__ x, const float* __restrict__ gamma,
    const float* __restrict__ beta, const float* __restrict__ qw,
    const float* __restrict__ kw, const float* __restrict__ vw,
    _Float16* __restrict__ Ah, _Float16* __restrict__ Wh) {
  const int t = threadIdx.x;

  if (blockIdx.x < MTOT) {
    // ---- LayerNorm branch: one row per block, 256 threads x 8 elems ----
    const int row = blockIdx.x;
    const float* xr = x + (size_t)row * HD;

    float4 v0 = reinterpret_cast<const float4*>(xr)[t * 2];
    float4 v1 = reinterpret_cast<const float4*>(xr)[t * 2 + 1];
    float xs[8] = {v0.x, v0.y, v0.z, v0.w, v1.x, v1.y, v1.z, v1.w};

    float s = 0.f, q = 0.f;
#pragma unroll
    for (int j = 0; j < 8; ++j) { s += xs[j]; q += xs[j] * xs[j]; }
#pragma unroll
    for (int off = 32; off; off >>= 1) {
      s += __shfl_down(s, off);
      q += __shfl_down(q, off);
    }
    __shared__ float red[8];
    const int wid = t >> 6, lane = t & 63;
    if (lane == 0) { red[wid] = s; red[4 + wid] = q; }
    __syncthreads();
    s = red[0] + red[1] + red[2] + red[3];
    q = red[4] + red[5] + red[6] + red[7];
    const float mu  = s * (1.f / HD);
    const float var = q * (1.f / HD) - mu * mu;
    const float rs  = rsqrtf(var + 1e-5f);

    float4 g0 = reinterpret_cast<const float4*>(gamma)[t * 2];
    float4 g1 = reinterpret_cast<const float4*>(gamma)[t * 2 + 1];
    float4 b0 = reinterpret_cast<const float4*>(beta)[t * 2];
    float4 b1 = reinterpret_cast<const float4*>(beta)[t * 2 + 1];
    float gs[8] = {g0.x, g0.y, g0.z, g0.w, g1.x, g1.y, g1.z, g1.w};
    float bs[8] = {b0.x, b0.y, b0.z, b0.w, b1.x, b1.y, b1.z, b1.w};

    f16x8 hv;
#pragma unroll
    for (int j = 0; j < 8; ++j) {
      float y = (xs[j] - mu) * rs * gs[j] + bs[j];
      hv[j] = (_Float16)y;
    }
    *reinterpret_cast<f16x8*>(&Ah[(size_t)row * HD + t * 8]) = hv;
  } else {
    // ---- Weight-convert branch: 3072 blocks, 1024 per matrix ----
    const int wb = blockIdx.x - MTOT;        // 0..3071
    const int m  = wb / 1024;                // which matrix
    const int b0 = wb % 1024;
    const float* src = (m == 0) ? qw : (m == 1) ? kw : vw;
    const size_t base = (size_t)m * HD * HD;
    const int total4 = HD * HD / 4;
    for (int i = b0 * 256 + t; i < total4; i += 1024 * 256) {
      float4 v = reinterpret_cast<const float4*>(src)[i];
      f16x4 hv;
      hv[0] = (_Float16)v.x; hv[1] = (_Float16)v.y;
      hv[2] = (_Float16)v.z; hv[3] = (_Float16)v.w;
      *reinterpret_cast<f16x4*>(&Wh[base + (size_t)i * 4]) = hv;
    }
  }
}

// ---------------------------------------------------------------------------
// Kernel 2: 256x256 8-phase fp16 GEMM (round-20 configuration, best
// measured).  Swizzled row-major LDS, coalesced staging, full A+B lookahead,
// counted phase-end lgkm fences.
// out[m][n] = sum_k A[m][k]*W_p[n][k] + bias_p[n]
//
// LDS (128 KiB, f16): A bufs @ {0,16384}, B bufs @ {32768,49152}; each buf =
// row-major [256][64] f16.  Swizzle: slot s of row r holds k-chunk s^(r&7);
// staging loads global column ((t&7)^((t>>3)&7)) -> line-coalesced; read
// k-terms kk0/kk1 per-thread constants (r15-r21 verified, 0 conflicts).
// Stage slots + VM6@P3 / VM6@P7 / VM0-tail vmcnt ledger (passed 8x).
// Phase-end counted lgkm fences per the r20 WAR derivation (passed).
// ---------------------------------------------------------------------------
__device__ __forceinline__ void gload16(const _Float16* g, _Float16* l) {
  __builtin_amdgcn_global_load_lds(
      (const __attribute__((address_space(1))) void*)g,
      (__attribute__((address_space(3))) void*)l, 16, 0, 0);
}

#define BAR()   asm volatile("s_barrier" ::: "memory")
#define LGKM4() asm volatile("s_waitcnt lgkmcnt(4)" ::: "memory")
#define LGKM8() asm volatile("s_waitcnt lgkmcnt(8)" ::: "memory")
#define VM6()   asm volatile("s_waitcnt vmcnt(6)" ::: "memory")
#define VM0()   asm volatile("s_waitcnt vmcnt(0)" ::: "memory")

#define LA(BUF, X, MH, KKV) \
  (*(const f16x8*)(lds + (BUF)*16384 + rA + (MH)*4096 + (X)*1024 + (KKV)))
#define LB(BUF, NR, KKV) \
  (*(const f16x8*)(lds + 32768 + (BUF)*16384 + rB + (NR)*1024 + (KKV)))

#define BHALF(BUF, SL, KKV) do { \
    bfr[0][SL]=LB(BUF,0,KKV); bfr[1][SL]=LB(BUF,1,KKV); \
    bfr[2][SL]=LB(BUF,2,KKV); bfr[3][SL]=LB(BUF,3,KKV); \
  } while (0)
#define ALD(T0, T1, T2, T3, BUF, MH, KKV) do { \
    T0 = LA(BUF, 0, MH, KKV); T1 = LA(BUF, 1, MH, KKV); \
    T2 = LA(BUF, 2, MH, KKV); T3 = LA(BUF, 3, MH, KKV); \
  } while (0)

#define MF(A, B, C) __builtin_amdgcn_mfma_f32_16x16x32_f16(A, B, C, 0, 0, 0)
#define MFMAS(A0, A1, A2, A3, MH, KS) do { \
    __builtin_amdgcn_s_setprio(1); \
    acc[(MH)*4+0][0]=MF(A0,bfr[0][KS],acc[(MH)*4+0][0]); \
    acc[(MH)*4+0][1]=MF(A0,bfr[1][KS],acc[(MH)*4+0][1]); \
    acc[(MH)*4+0][2]=MF(A0,bfr[2][KS],acc[(MH)*4+0][2]); \
    acc[(MH)*4+0][3]=MF(A0,bfr[3][KS],acc[(MH)*4+0][3]); \
    acc[(MH)*4+1][0]=MF(A1,bfr[0][KS],acc[(MH)*4+1][0]); \
    acc[(MH)*4+1][1]=MF(A1,bfr[1][KS],acc[(MH)*4+1][1]); \
    acc[(MH)*4+1][2]=MF(A1,bfr[2][KS],acc[(MH)*4+1][2]); \
    acc[(MH)*4+1][3]=MF(A1,bfr[3][KS],acc[(MH)*4+1][3]); \
    acc[(MH)*4+2][0]=MF(A2,bfr[0][KS],acc[(MH)*4+2][0]); \
    acc[(MH)*4+2][1]=MF(A2,bfr[1][KS],acc[(MH)*4+2][1]); \
    acc[(MH)*4+2][2]=MF(A2,bfr[2][KS],acc[(MH)*4+2][2]); \
    acc[(MH)*4+2][3]=MF(A2,bfr[3][KS],acc[(MH)*4+2][3]); \
    acc[(MH)*4+3][0]=MF(A3,bfr[0][KS],acc[(MH)*4+3][0]); \
    acc[(MH)*4+3][1]=MF(A3,bfr[1][KS],acc[(MH)*4+3][1]); \
    acc[(MH)*4+3][2]=MF(A3,bfr[2][KS],acc[(MH)*4+3][2]); \
    acc[(MH)*4+3][3]=MF(A3,bfr[3][KS],acc[(MH)*4+3][3]); \
    __builtin_amdgcn_s_setprio(0); \
  } while (0)

__global__ __launch_bounds__(512, 2) void qkv_gemm_kernel(
    const _Float16* __restrict__ Ah, const _Float16* __restrict__ Wh,
    const float* __restrict__ qb, const float* __restrict__ kb,
    const float* __restrict__ vb, float* __restrict__ out) {
  extern __shared__ _Float16 lds[];   // 131072 B

  const int t    = threadIdx.x;
  const int lane = t & 63;
  const int wid  = t >> 6;            // 0..7
  const int wm   = wid >> 2;          // 0..1 (M)
  const int wn   = wid & 3;           // 0..3 (N)
  const int fr   = lane & 15;
  const int fq   = lane >> 4;

  const int n0  = blockIdx.x * 256;
  const int m0  = blockIdx.y * 256;
  const int p   = n0 >> 11;
  const int ln0 = n0 & (HD - 1);
  const _Float16* Ag  = Ah + (size_t)m0 * HD;
  const _Float16* Bgp = Wh + (size_t)p * HD * HD + (size_t)ln0 * HD;
  const float* bias = (p == 0) ? qb : (p == 1) ? kb : vb;

  // Staging invariants (coalesced + inverse-swizzled source).
  const int srow = t >> 3;                              // 0..63
  const int scol = ((t & 7) ^ (srow & 7)) * 8;          // f16 offset in row
  // Fragment-read invariants.
  const int rA  = (wm * 128 + fr) * 64;
  const int rB  = (wn * 64 + fr) * 64;
  const int kk0 = ((fq) ^ (fr & 7)) * 8;
  const int kk1 = ((4 + fq) ^ (fr & 7)) * 8;

  auto stA = [&](int buf, int hf, int kt) {
    const _Float16* g = Ag + (size_t)(hf * 64 + srow) * HD + kt * 64 + scol;
    _Float16* l = lds + buf * 16384 + (hf * 512 + t) * 8;
    gload16(g, l);
    gload16(g + (size_t)128 * HD, l + 8192);
  };
  auto stB = [&](int buf, int hf, int kt) {
    const _Float16* g = Bgp + (size_t)(hf * 64 + srow) * HD + kt * 64 + scol;
    _Float16* l = lds + 32768 + buf * 16384 + (hf * 512 + t) * 8;
    gload16(g, l);
    gload16(g + (size_t)128 * HD, l + 8192);
  };

  f32x4 acc[8][4] = {};

  // Fragment registers: B rotating set (32 VGPR) + A double sets x/y (16+16).
  f16x8 bfr[4][2];
  f16x8 x0, x1, x2, x3;
  f16x8 y0, y1, y2, y3;

  // Prologue: buf0 <- K-tile 0 (4 halves), buf1 <- K-tile 1 (3 halves).
  // vmcnt(6) = 3 calls in flight -> buf0 fully landed.
  stB(0, 0, 0); stB(0, 1, 0); stA(0, 0, 0); stA(0, 1, 0);
  stB(1, 0, 1); stB(1, 1, 1); stA(1, 0, 1);
  VM6();
  BAR();
  BHALF(0, 0, kk0);
  ALD(x0, x1, x2, x3, 0, 0, kk0);

#pragma unroll 1
  for (int i = 0; i < NIT; ++i) {
    const bool nl = (i < NIT - 1);
    const int kt1 = 2 * i + 1, kt2 = 2 * i + 2, kt3 = 2 * i + 3;

    // ---- P0 ----
    stA(1, 1, kt1);
    BHALF(0, 1, kk1);
    ALD(y0, y1, y2, y3, 0, 0, kk1);
    MFMAS(x0, x1, x2, x3, 0, 0);
    LGKM4(); BAR();

    // ---- P1 ----
    if (nl) stB(0, 0, kt2);
    ALD(x0, x1, x2, x3, 0, 1, kk0);
    MFMAS(y0, y1, y2, y3, 0, 1);
    LGKM4(); BAR();

    // ---- P2 ----
    if (nl) stB(0, 1, kt2);
    ALD(y0, y1, y2, y3, 0, 1, kk1);
    MFMAS(x0, x1, x2, x3, 1, 0);
    LGKM4(); BAR();

    // ---- P3 ----
    if (nl) { stA(0, 0, kt2); VM6(); } else { VM0(); }
    BHALF(1, 0, kk0);
    ALD(x0, x1, x2, x3, 1, 0, kk0);
    MFMAS(y0, y1, y2, y3, 1, 1);
    LGKM8(); BAR();

    // ---- P4 ----
    if (nl) stA(0, 1, kt2);
    BHALF(1, 1, kk1);
    ALD(y0, y1, y2, y3, 1, 0, kk1);
    MFMAS(x0, x1, x2, x3, 0, 0);
    LGKM4(); BAR();

    // ---- P5 ----
    if (nl) stB(1, 0, kt3);
    ALD(x0, x1, x2, x3, 1, 1, kk0);
    MFMAS(y0, y1, y2, y3, 0, 1);
    LGKM4(); BAR();

    // ---- P6 ----
    if (nl) stB(1, 1, kt3);
    ALD(y0, y1, y2, y3, 1, 1, kk1);
    MFMAS(x0, x1, x2, x3, 1, 0);
    LGKM4(); BAR();

    // ---- P7 ----
    if (nl) {
      stA(1, 0, kt3);
      VM6();
      BHALF(0, 0, kk0);
      ALD(x0, x1, x2, x3, 0, 0, kk0);
    }
    MFMAS(y0, y1, y2, y3, 1, 1);
    LGKM8(); BAR();
  }

  // Epilogue: C/D layout col = lane&15, row = (lane>>4)*4 + reg.
  float bv[4];
#pragma unroll
  for (int nr = 0; nr < 4; ++nr)
    bv[nr] = bias[(ln0 + wn * 64 + nr * 16 + fr)];
#pragma unroll
  for (int mr = 0; mr < 8; ++mr) {
    const int r0 = m0 + wm * 128 + mr * 16 + fq * 4;
#pragma unroll
    for (int nr = 0; nr < 4; ++nr) {
      const int cg = n0 + wn * 64 + nr * 16 + fr;
      f32x4 v = acc[mr][nr];
#pragma unroll
      for (int r = 0; r < 4; ++r)
        out[(size_t)(r0 + r) * NTOT + cg] = v[r] + bv[nr];
    }
  }
}

// ---------------------------------------------------------------------------
extern "C" void kernel_launch(void* const* d_in, const int* in_sizes, int n_in,
                              void* d_out, int out_size, void* d_ws,
                              size_t ws_size, hipStream_t stream) {
  const float* x     = (const float*)d_in[0];
  const float* gamma = (const float*)d_in[1];
  const float* beta  = (const float*)d_in[2];
  const float* qw    = (const float*)d_in[3];
  const float* qb    = (const float*)d_in[4];
  const float* kw    = (const float*)d_in[5];
  const float* kbia  = (const float*)d_in[6];
  const float* vw    = (const float*)d_in[7];
  const float* vb    = (const float*)d_in[8];
  float* out = (float*)d_out;

  // Workspace: [0, 32M) normed fp16 [8192][2048]; [32M, 56M) W fp16 [3][2048][2048]
  char* ws = (char*)d_ws;
  _Float16* Ahp = (_Float16*)(ws);
  _Float16* Whp = (_Float16*)(ws + (size_t)MTOT * HD * 2);

  (void)hipFuncSetAttribute((const void*)qkv_gemm_kernel,
                            hipFuncAttributeMaxDynamicSharedMemorySize, 131072);

  prep_kernel<<<MTOT + 3072, 256, 0, stream>>>(x, gamma, beta, qw, kw, vw,
                                               Ahp, Whp);
  qkv_gemm_kernel<<<dim3(NTOT / 256, MTOT / 256), 512, 131072, stream>>>(
      Ahp, Whp, qb, kbia, vb, out);
}